// Round 16
// baseline (995.541 us; speedup 1.0000x reference)
//
#include <hip/hip_runtime.h>
#include <stdint.h>
#include <math.h>

// RNN predictor: B=2048, T=1024 teacher + FUT=64 AR, H=128.
// Round-16: 4 independent chains per CU, register budget <= 128 VGPR.
//  - SPB=2, grid=1024, 4 waves x 256 thr, __launch_bounds__(256,4):
//    each SIMD hosts 4 waves from 4 INDEPENDENT blocks -> anti-phased
//    latency hiding (R11's 2-chain win, doubled).
//  - SINGLE-fp16 weights (no hi/lo): 12 MFMA/wave-step (8 S + 4 o),
//    48 weight VGPRs -> total ~110 <= 128: no AGPR parking, no copy tax
//    (R12's 153-instr/step VALU mystery = operand copies at cap 128).
//    Numerics: dW ~ 1.2e-5 rms -> closed-loop h error ~2e-4 rms, tails
//    ~1-2e-3 < 4e-3 threshold. h single fp16 (proven R11+).
//  - piggyback o-MFMA (wout as B col 0): o_{i-1} materializes in-step;
//    no shfl-reduce, no opart. AR feedback = 2 intra-wave shfls.
//  - masked A-reads (l15<2; zero-init regs carry rows 2-15), masked
//    h'-writes (g==0, 4 ds_write_b16). All LDS access <=2-way banks
//    (no swizzle needed at 256B row stride with these patterns).
//  - one barrier/step; 64-entry ring flushed as f32x4.

#define TLEN  1024
#define FUT   64
#define HID   128
#define SPB   2
#define NT    256
#define NSTEP (TLEN + FUT)

typedef float f32x4 __attribute__((ext_vector_type(4)));
typedef _Float16 f16x8 __attribute__((ext_vector_type(8)));
typedef uint32_t u32x4 __attribute__((ext_vector_type(4)));

__device__ __forceinline__ f16x8 asf16(u32x4 v) {
    return __builtin_bit_cast(f16x8, v);
}
__device__ __forceinline__ float fast_tanh(float v) {
    return 1.0f - 2.0f / (__expf(2.0f * v) + 1.0f);   // saturates correctly
}

__global__ __launch_bounds__(NT, 4) void rnn_kernel(
    const float* __restrict__ x,      // [B, T]
    const float* __restrict__ W_ih,   // [H, 1]
    const float* __restrict__ W_hh,   // [H, H]
    const float* __restrict__ b_ih,   // [H]
    const float* __restrict__ b_hh,   // [H]
    const float* __restrict__ W_out,  // [1, H]
    const float* __restrict__ b_out,  // [1]
    float* __restrict__ out)          // [B, T+FUT]
{
    // h: [p][row 0..1][k] fp16, row stride 256B. Only rows 0-1 exist.
    __shared__ __align__(16) unsigned short hbuf[2][SPB * HID];   // 1KB
    __shared__ __align__(16) float xstg[128][SPB];                // 1KB
    __shared__ __align__(16) float ring[2][SPB][68];              // ~1.1KB

    const int tid  = threadIdx.x;
    const int lane = tid & 63;
    const int wid  = tid >> 6;        // wave w: cols 32w..32w+31 (2 tiles)
    const int l15  = lane & 15;
    const int g    = lane >> 4;
    const int s0   = blockIdx.x * SPB;

    // ---- weight B-fragments, single fp16: col j, k = 32kt + 8g + e ----
    const int j0 = 32 * wid + l15;
    const int j1 = j0 + 16;
    f16x8 W0[4], W1[4], Wo[4];
    {
        const float* r0 = W_hh + (size_t)j0 * HID;
        const float* r1 = W_hh + (size_t)j1 * HID;
        #pragma unroll
        for (int kt = 0; kt < 4; ++kt) {
            #pragma unroll
            for (int e = 0; e < 8; ++e) {
                const int k = 32 * kt + 8 * g + e;
                W0[kt][e] = (_Float16)r0[k];
                W1[kt][e] = (_Float16)r1[k];
                Wo[kt][e] = (l15 == 0) ? (_Float16)W_out[k] : (_Float16)0.0f;
            }
        }
    }
    const float bias0 = b_ih[j0] + b_hh[j0];
    const float bias1 = b_ih[j1] + b_hh[j1];
    const float wih0  = W_ih[j0], wih1 = W_ih[j1];
    const float bo    = b_out[0];

    // A-read: lane l15<2 reads row l15, 16B at 64kt+16g (2-way banks, free)
    int aoff[4];
    #pragma unroll
    for (int kt = 0; kt < 4; ++kt)
        aoff[kt] = l15 * 256 + 64 * kt + 16 * g;

    for (int idx = tid; idx < SPB * HID; idx += NT)   // both parities (u32)
        ((uint32_t*)hbuf)[idx] = 0;
    __syncthreads();

    // A-frags zeroed once; masked loads keep l15>=2 lanes at zero forever.
    u32x4 A_[4];
    #pragma unroll
    for (int kt = 0; kt < 4; ++kt) A_[kt] = (u32x4){0, 0, 0, 0};

    for (int i = 0; i < NSTEP; ++i) {
        const int p = i & 1;

        // refill x chunk every 128 teacher steps (coalesced along t)
        if (i < TLEN && (i & 127) == 0) {
            const int t = tid & 127, s = tid >> 7;   // 256 thr = 128t x 2s
            xstg[t][s] = x[(size_t)(s0 + s) * TLEN + (i + t)];
            __syncthreads();
        }

        // flush a full 64-entry output ring (o_{i-65}..o_{i-2})
        if (i > 64 && (i & 63) == 1 && tid < 16 * SPB) {
            const int q = ((i - 65) >> 6) & 1;
            const int s = tid >> 4, c4 = (tid & 15) * 4;
            const f32x4 v = *(const f32x4*)&ring[q][s][c4];
            *(f32x4*)&out[(size_t)(s0 + s) * NSTEP + (i - 65) + c4] = v;
        }

        // A-fragments of h_i (rows 0-1; other lanes keep zeros)
        const char* hb = (const char*)hbuf[p];
        if (l15 < SPB) {
            #pragma unroll
            for (int kt = 0; kt < 4; ++kt)
                A_[kt] = *(const u32x4*)(hb + aoff[kt]);
        }

        // 12 MFMA in 3 independent chains
        f32x4 sA = {0.f,0.f,0.f,0.f}, sB = sA, ov = sA;
        #pragma unroll
        for (int kt = 0; kt < 4; ++kt) {
            sA = __builtin_amdgcn_mfma_f32_16x16x32_f16(asf16(A_[kt]), W0[kt], sA, 0, 0, 0);
            sB = __builtin_amdgcn_mfma_f32_16x16x32_f16(asf16(A_[kt]), W1[kt], sB, 0, 0, 0);
            ov = __builtin_amdgcn_mfma_f32_16x16x32_f16(asf16(A_[kt]), Wo[kt], ov, 0, 0, 0);
        }

        // o_{i-1} for rows 0,1 -- valid at lane 0 (g==0, l15==0)
        const float oval0 = ov[0] + bo;
        const float oval1 = ov[1] + bo;
        if (i > 0 && wid == 0 && lane == 0) {
            const int q = ((i - 1) >> 6) & 1;
            const int c = (i - 1) & 63;
            ring[q][0][c] = oval0;
            ring[q][1][c] = oval1;
        }

        // per-sample inputs (uniform branch)
        float in0, in1;
        if (i < TLEN) {
            in0 = xstg[i & 127][0];      // broadcast reads
            in1 = xstg[i & 127][1];
        } else {
            in0 = __shfl(oval0, 0);      // intra-wave: each wave has its own
            in1 = __shfl(oval1, 0);
        }

        // epilogue: rows 0,1 x cols j0,j1 (meaningful at g==0 lanes)
        const float h00 = fast_tanh(sA[0] + bias0 + in0 * wih0);
        const float h01 = fast_tanh(sB[0] + bias1 + in0 * wih1);
        const float h10 = fast_tanh(sA[1] + bias0 + in1 * wih0);
        const float h11 = fast_tanh(sB[1] + bias1 + in1 * wih1);

        if (g == 0) {
            char* hw = (char*)hbuf[p ^ 1];
            *(unsigned short*)(hw + 2 * j0)       = __builtin_bit_cast(unsigned short, (_Float16)h00);
            *(unsigned short*)(hw + 2 * j1)       = __builtin_bit_cast(unsigned short, (_Float16)h01);
            *(unsigned short*)(hw + 256 + 2 * j0) = __builtin_bit_cast(unsigned short, (_Float16)h10);
            *(unsigned short*)(hw + 256 + 2 * j1) = __builtin_bit_cast(unsigned short, (_Float16)h11);
        }
        __syncthreads();   // the one per-step barrier
    }

    // tail: o_{NSTEP-1} from final state (parity NSTEP&1 = 0)
    {
        const char* hb = (const char*)hbuf[NSTEP & 1];
        if (l15 < SPB) {
            #pragma unroll
            for (int kt = 0; kt < 4; ++kt)
                A_[kt] = *(const u32x4*)(hb + aoff[kt]);
        }
        f32x4 ov = {0.f,0.f,0.f,0.f};
        #pragma unroll
        for (int kt = 0; kt < 4; ++kt)
            ov = __builtin_amdgcn_mfma_f32_16x16x32_f16(asf16(A_[kt]), Wo[kt], ov, 0, 0, 0);
        if (wid == 0 && lane == 0) {
            ring[0][0][63] = ov[0] + bo;    // (1087>>6)&1 = 0
            ring[0][1][63] = ov[1] + bo;
        }
    }
    __syncthreads();
    if (tid < 16 * SPB) {   // flush t = 1024..1087 (ring parity 0)
        const int s = tid >> 4, c4 = (tid & 15) * 4;
        const f32x4 v = *(const f32x4*)&ring[0][s][c4];
        *(f32x4*)&out[(size_t)(s0 + s) * NSTEP + TLEN + c4] = v;
    }
}

extern "C" void kernel_launch(void* const* d_in, const int* in_sizes, int n_in,
                              void* d_out, int out_size, void* d_ws, size_t ws_size,
                              hipStream_t stream) {
    const float* x     = (const float*)d_in[0];
    const float* W_ih  = (const float*)d_in[1];
    const float* W_hh  = (const float*)d_in[2];
    const float* b_ih  = (const float*)d_in[3];
    const float* b_hh  = (const float*)d_in[4];
    const float* W_out = (const float*)d_in[5];
    const float* b_out = (const float*)d_in[6];
    float* out = (float*)d_out;

    dim3 grid(2048 / SPB);   // 1024 blocks -> 4 per CU
    dim3 block(NT);
    rnn_kernel<<<grid, block, 0, stream>>>(x, W_ih, W_hh, b_ih, b_hh,
                                           W_out, b_out, out);
}

// Round 17
// 391.190 us; speedup vs baseline: 2.5449x; 2.5449x over previous
//
#include <hip/hip_runtime.h>
#include <stdint.h>
#include <math.h>

// RNN predictor: B=2048, T=1024 teacher + FUT=64 AR, H=128.
// Round-17: R11 geometry (best, 729us) + R16 arithmetic (single-fp16 W,
// validated at the absmax floor) + o-via-MFMA + split loops.
//  - SPB=4, 4 waves, grid 512, (256,2): 2 anti-phased blocks/CU (proven).
//  - single-fp16 weights: 8 S-MFMA/wave-step (2 j-tiles x 4 kt).
//  - piggyback o-MFMA (Wo as B col 0): o_{i-1} materializes in-step; no
//    shfl-reduce, no opart round-trip. Teacher: wave 0 only. AR: all waves
//    (feedback = ONE intra-wave shfl from lane g*16).
//  - teacher/AR loops split; #pragma unroll 2 folds parity addressing.
//  - pi-permuted LDS layout + single ds_write_b32 per lane (R11-verified).

#define TLEN  1024
#define FUT   64
#define HID   128
#define SPB   4
#define NT    256
#define NSTEP (TLEN + FUT)

typedef float f32x4 __attribute__((ext_vector_type(4)));
typedef _Float16 f16x8 __attribute__((ext_vector_type(8)));
typedef uint32_t u32x4 __attribute__((ext_vector_type(4)));

__device__ __forceinline__ f16x8 asf16(u32x4 v) {
    return __builtin_bit_cast(f16x8, v);
}
__device__ __forceinline__ float fast_tanh(float v) {
    return 1.0f - 2.0f / (__expf(2.0f * v) + 1.0f);   // saturates correctly
}

__global__ __launch_bounds__(NT, 2) void rnn_kernel(
    const float* __restrict__ x,      // [B, T]
    const float* __restrict__ W_ih,   // [H, 1]
    const float* __restrict__ W_hh,   // [H, H]
    const float* __restrict__ b_ih,   // [H]
    const float* __restrict__ b_hh,   // [H]
    const float* __restrict__ W_out,  // [1, H]
    const float* __restrict__ b_out,  // [1]
    float* __restrict__ out)          // [B, T+FUT]
{
    // h: [p][row s=0..3][pi(k)] fp16, row 256B, byte ^= (s<<5) on reads/writes
    __shared__ __align__(16) unsigned short hbuf[2][SPB * HID];  // 2KB
    __shared__ __align__(16) float xstg[128][8];                 // cols 0..3
    __shared__ __align__(16) float ring[2][SPB][68];             // o ring

    const int tid  = threadIdx.x;
    const int lane = tid & 63;
    const int wid  = tid >> 6;        // wave w: cols 32w..32w+31
    const int l15  = lane & 15;
    const int g    = lane >> 4;       // = sample index in epilogue
    const int s0   = blockIdx.x * SPB;

    // ---- weight B-fragments, single fp16; pi: slot(kt,g,e) -> k=16e+4kt+g
    const int j0 = 32 * wid + l15;
    const int j1 = j0 + 16;
    f16x8 W0[4], W1[4], Wo[4];
    {
        const float* r0 = W_hh + (size_t)j0 * HID;
        const float* r1 = W_hh + (size_t)j1 * HID;
        #pragma unroll
        for (int kt = 0; kt < 4; ++kt) {
            #pragma unroll
            for (int e = 0; e < 8; ++e) {
                const int k = 16 * e + 4 * kt + g;
                W0[kt][e] = (_Float16)r0[k];
                W1[kt][e] = (_Float16)r1[k];
                Wo[kt][e] = (l15 == 0) ? (_Float16)W_out[k] : (_Float16)0.0f;
            }
        }
    }
    const float bias0 = b_ih[j0] + b_hh[j0];
    const float bias1 = b_ih[j1] + b_hh[j1];
    const float wih0  = W_ih[j0], wih1 = W_ih[j1];
    const float bo    = b_out[0];

    // ---- LDS byte offsets (R11-verified) ----
    const int s_ = l15 >> 2;          // A row, active lanes l15&3==0
    int aoff[4];
    #pragma unroll
    for (int kt = 0; kt < 4; ++kt)
        aoff[kt] = s_ * 256 + (((4 * kt + g) * 16) ^ (s_ << 5));
    const int woff = g * 256 + ((l15 * 16 + wid * 4) ^ (g << 5));

    for (int idx = tid; idx < SPB * HID; idx += NT)   // both parities (u32)
        ((uint32_t*)hbuf)[idx] = 0;
    __syncthreads();

    // A-frags zeroed once; masked loads keep inactive lanes at zero.
    u32x4 A_[4];
    #pragma unroll
    for (int kt = 0; kt < 4; ++kt) A_[kt] = (u32x4){0, 0, 0, 0};

    // ================= teacher-forced loop =================
    #pragma unroll 2
    for (int i = 0; i < TLEN; ++i) {
        const int p = i & 1;

        if ((i & 127) == 0) {         // refill x chunk (coalesced along t)
            #pragma unroll
            for (int pass = 0; pass < 2; ++pass) {
                const int idx = pass * NT + tid;
                const int t = idx & 127, s = idx >> 7;
                xstg[t][s] = x[(size_t)(s0 + s) * TLEN + (i + t)];
            }
            __syncthreads();
        }
        if (i > 64 && (i & 63) == 1 && tid < 16 * SPB) {   // flush o ring
            const int q = ((i - 65) >> 6) & 1;
            const int s = tid >> 4, c4 = (tid & 15) * 4;
            const f32x4 v = *(const f32x4*)&ring[q][s][c4];
            *(f32x4*)&out[(size_t)(s0 + s) * NSTEP + (i - 65) + c4] = v;
        }

        const char* hb = (const char*)hbuf[p];
        if ((l15 & 3) == 0) {
            #pragma unroll
            for (int kt = 0; kt < 4; ++kt)
                A_[kt] = *(const u32x4*)(hb + aoff[kt]);
        }

        // 8 S-MFMA (2 chains); o-MFMA only on wave 0
        f32x4 sA = {0.f,0.f,0.f,0.f}, sB = sA;
        #pragma unroll
        for (int kt = 0; kt < 4; ++kt) {
            sA = __builtin_amdgcn_mfma_f32_16x16x32_f16(asf16(A_[kt]), W0[kt], sA, 0, 0, 0);
            sB = __builtin_amdgcn_mfma_f32_16x16x32_f16(asf16(A_[kt]), W1[kt], sB, 0, 0, 0);
        }
        if (wid == 0) {
            f32x4 ov = {0.f,0.f,0.f,0.f};
            #pragma unroll
            for (int kt = 0; kt < 4; ++kt)
                ov = __builtin_amdgcn_mfma_f32_16x16x32_f16(asf16(A_[kt]), Wo[kt], ov, 0, 0, 0);
            // o_{i-1}[sample g] at lanes l15==0 (C row 4g, col 0)
            if (i > 0 && l15 == 0)
                ring[((i - 1) >> 6) & 1][g][(i - 1) & 63] = ov[0] + bo;
        }

        const float in = xstg[i & 127][g];
        const float h0 = fast_tanh(sA[0] + bias0 + in * wih0);
        const float h1 = fast_tanh(sB[0] + bias1 + in * wih1);
        const uint32_t pv = (uint32_t)__builtin_bit_cast(unsigned short, (_Float16)h0)
                          | ((uint32_t)__builtin_bit_cast(unsigned short, (_Float16)h1) << 16);
        *(uint32_t*)((char*)hbuf[p ^ 1] + woff) = pv;

        __syncthreads();
    }

    // ================= autoregressive loop =================
    #pragma unroll 2
    for (int i = TLEN; i < NSTEP; ++i) {
        const int p = i & 1;

        if ((i & 63) == 1 && tid < 16 * SPB) {   // flush (fires at i=1025)
            const int q = ((i - 65) >> 6) & 1;
            const int s = tid >> 4, c4 = (tid & 15) * 4;
            const f32x4 v = *(const f32x4*)&ring[q][s][c4];
            *(f32x4*)&out[(size_t)(s0 + s) * NSTEP + (i - 65) + c4] = v;
        }

        const char* hb = (const char*)hbuf[p];
        if ((l15 & 3) == 0) {
            #pragma unroll
            for (int kt = 0; kt < 4; ++kt)
                A_[kt] = *(const u32x4*)(hb + aoff[kt]);
        }

        // 12 MFMA: S (2 chains) + o (all waves; each needs it for feedback)
        f32x4 sA = {0.f,0.f,0.f,0.f}, sB = sA, ov = sA;
        #pragma unroll
        for (int kt = 0; kt < 4; ++kt) {
            sA = __builtin_amdgcn_mfma_f32_16x16x32_f16(asf16(A_[kt]), W0[kt], sA, 0, 0, 0);
            sB = __builtin_amdgcn_mfma_f32_16x16x32_f16(asf16(A_[kt]), W1[kt], sB, 0, 0, 0);
            ov = __builtin_amdgcn_mfma_f32_16x16x32_f16(asf16(A_[kt]), Wo[kt], ov, 0, 0, 0);
        }
        const float oval = ov[0] + bo;          // valid at lanes l15==0
        if (wid == 0 && l15 == 0)
            ring[((i - 1) >> 6) & 1][g][(i - 1) & 63] = oval;

        // feedback: sample g's o sits at lane g*16 (reg 0)
        const float in = __shfl(oval, g << 4);
        const float h0 = fast_tanh(sA[0] + bias0 + in * wih0);
        const float h1 = fast_tanh(sB[0] + bias1 + in * wih1);
        const uint32_t pv = (uint32_t)__builtin_bit_cast(unsigned short, (_Float16)h0)
                          | ((uint32_t)__builtin_bit_cast(unsigned short, (_Float16)h1) << 16);
        *(uint32_t*)((char*)hbuf[p ^ 1] + woff) = pv;

        __syncthreads();
    }

    // tail: o_{NSTEP-1} = wout . h_{NSTEP} (state in hbuf[NSTEP&1] = [0])
    {
        const char* hb = (const char*)hbuf[NSTEP & 1];
        if ((l15 & 3) == 0) {
            #pragma unroll
            for (int kt = 0; kt < 4; ++kt)
                A_[kt] = *(const u32x4*)(hb + aoff[kt]);
        }
        f32x4 ov = {0.f,0.f,0.f,0.f};
        #pragma unroll
        for (int kt = 0; kt < 4; ++kt)
            ov = __builtin_amdgcn_mfma_f32_16x16x32_f16(asf16(A_[kt]), Wo[kt], ov, 0, 0, 0);
        if (wid == 0 && l15 == 0)
            ring[0][g][63] = ov[0] + bo;        // (1087>>6)&1 = 0
    }
    __syncthreads();
    if (tid < 16 * SPB) {   // flush t = 1024..1087 (ring parity 0)
        const int s = tid >> 4, c4 = (tid & 15) * 4;
        const f32x4 v = *(const f32x4*)&ring[0][s][c4];
        *(f32x4*)&out[(size_t)(s0 + s) * NSTEP + TLEN + c4] = v;
    }
}

extern "C" void kernel_launch(void* const* d_in, const int* in_sizes, int n_in,
                              void* d_out, int out_size, void* d_ws, size_t ws_size,
                              hipStream_t stream) {
    const float* x     = (const float*)d_in[0];
    const float* W_ih  = (const float*)d_in[1];
    const float* W_hh  = (const float*)d_in[2];
    const float* b_ih  = (const float*)d_in[3];
    const float* b_hh  = (const float*)d_in[4];
    const float* W_out = (const float*)d_in[5];
    const float* b_out = (const float*)d_in[6];
    float* out = (float*)d_out;

    dim3 grid(2048 / SPB);   // 512 blocks -> 2 per CU
    dim3 block(NT);
    rnn_kernel<<<grid, block, 0, stream>>>(x, W_ih, W_hh, b_ih, b_hh,
                                           W_out, b_out, out);
}